// Round 7
// baseline (299.609 us; speedup 1.0000x reference)
//
#include <hip/hip_runtime.h>
#include <stdint.h>

#define Bz 2
#define Sz 2048
#define Dz 1024
#define Hz 16
#define HDz 64
#define Mz (Bz*Sz)   // 4096

typedef unsigned short u16;
typedef __attribute__((ext_vector_type(8))) __bf16 bf16x8;
typedef __attribute__((ext_vector_type(8))) unsigned short u16x8;
typedef __attribute__((ext_vector_type(4))) float f32x4;

#define C1 0.1803368801111243f   /* 0.125 * log2(e) */

__device__ __forceinline__ u16 f2bf(float f) {
  union { float f; unsigned u; } v; v.f = f;
  unsigned r = v.u + 0x7fffu + ((v.u >> 16) & 1u);
  return (u16)(r >> 16);
}

// pack two fp32 into adjacent bf16 (round-half-up), low = a, high = b
__device__ __forceinline__ unsigned packbf(float a, float b) {
  unsigned ua = __builtin_bit_cast(unsigned, a);
  unsigned ub = __builtin_bit_cast(unsigned, b);
  return ((ua + 0x8000u) >> 16) | ((ub + 0x8000u) & 0xFFFF0000u);
}

__device__ __forceinline__ bf16x8 mk8(unsigned a, unsigned b, unsigned c, unsigned d) {
  union { unsigned u[4]; bf16x8 v; } x;
  x.u[0] = a; x.u[1] = b; x.u[2] = c; x.u[3] = d;
  return x.v;
}

__device__ __forceinline__ void async16(void* lds, const void* g) {
  __builtin_amdgcn_global_load_lds(
      (const __attribute__((address_space(1))) unsigned int*)g,
      (__attribute__((address_space(3))) unsigned int*)lds, 16, 0, 0);
}

// ---------- fused prep: fp32->bf16 for q/k/v AND weight transpose+convert ----------
__global__ void __launch_bounds__(256)
prep_kernel(const float* __restrict__ q, const float* __restrict__ k, const float* __restrict__ v,
            const float* __restrict__ w0, const float* __restrict__ w1,
            const float* __restrict__ w2, const float* __restrict__ w3,
            u16* __restrict__ xq, u16* __restrict__ xk, u16* __restrict__ xv,
            u16* __restrict__ Wt) {
  __shared__ __align__(16) float t[32][33];
  const int bid = blockIdx.x, tid = threadIdx.x;
  if (bid < 12288) {
    const int sel = bid >> 12;
    const int i = ((bid & 4095) << 8) + tid;
    const float* in = sel == 0 ? q : sel == 1 ? k : v;
    u16* out = sel == 0 ? xq : sel == 1 ? xk : xv;
    float4 tv = ((const float4*)in)[i];
    ((ushort4*)out)[i] = make_ushort4(f2bf(tv.x), f2bf(tv.y), f2bf(tv.z), f2bf(tv.w));
  } else {
    const int idx = bid - 12288;
    const int z = idx >> 10, r = idx & 1023;
    const int n0 = (r & 31) * 32, k0 = (r >> 5) * 32;
    const float* W = z == 0 ? w0 : z == 1 ? w1 : z == 2 ? w2 : w3;
    u16* o = Wt + (size_t)z * Dz * Dz;
    const int x = tid & 31, y = tid >> 5;   // 32 x 8
#pragma unroll
    for (int i = 0; i < 4; ++i)
      t[y + i*8][x] = W[(size_t)(k0 + y + i*8) * Dz + n0 + x];
    __syncthreads();
#pragma unroll
    for (int i = 0; i < 4; ++i)
      o[(size_t)(n0 + y + i*8) * Dz + k0 + x] = f2bf(t[x][y + i*8]);
  }
}

// ---- Vp[B*S][D] bf16 -> Vt[B][H][HD][S] bf16 (per-head transpose, coalesced) ----
__global__ void __launch_bounds__(256)
vtrans_kernel(const u16* __restrict__ Vp, u16* __restrict__ Vt) {
  __shared__ __align__(16) u16 t[64][72];
  int s0 = blockIdx.x * 64, bh = blockIdx.y;
  int b = bh >> 4;
  int h = bh & 15;
  int tid = threadIdx.x;
#pragma unroll
  for (int p = 0; p < 4; ++p) {
    int c = p * 256 + tid;
    int row = c >> 4, off = (c & 15) * 4;
    ushort4 v = *(const ushort4*)(Vp + (size_t)(b * Sz + s0 + row) * Dz + h * 64 + off);
    *(ushort4*)&t[row][off] = v;
  }
  __syncthreads();
#pragma unroll
  for (int p = 0; p < 4; ++p) {
    int c = p * 256 + tid;
    int d = c >> 4, sc = (c & 15) * 4;
    ushort4 v = make_ushort4(t[sc + 0][d], t[sc + 1][d], t[sc + 2][d], t[sc + 3][d]);
    *(ushort4*)(Vt + (size_t)(bh * 64 + d) * Sz + s0 + sc) = v;
  }
}

// -------- fused QKV GEMM: 128x128 tile; blockIdx.x>>3 selects {Q,K,V}; plain epilogue --------
__global__ void __launch_bounds__(256)
gemm_qkv(const u16* __restrict__ xq, const u16* __restrict__ xk, const u16* __restrict__ xv,
         const u16* __restrict__ Wt3,
         const float* __restrict__ bq, const float* __restrict__ bk, const float* __restrict__ bv,
         u16* __restrict__ Qp, u16* __restrict__ Kp, u16* __restrict__ Vp)
{
  __shared__ __align__(16) u16 lA[128][32];
  __shared__ __align__(16) u16 lB[128][32];
  const int sel = blockIdx.x >> 3;
  const int n0 = (blockIdx.x & 7) * 128;
  const int m0 = blockIdx.y * 128;
  const u16* A = sel == 0 ? xq : sel == 1 ? xk : xv;
  const u16* Bt = Wt3 + (size_t)sel * Dz * Dz;
  const float* bias = sel == 0 ? bq : sel == 1 ? bk : bv;
  u16* Cv = sel == 0 ? Qp : sel == 1 ? Kp : Vp;

  const int tid = threadIdx.x;
  const int w = tid >> 6, lane = tid & 63;
  const int wm = (w >> 1) * 64, wn = (w & 1) * 64;
  const int l16 = lane & 15, qd = lane >> 4;

  f32x4 acc[4][4];
#pragma unroll
  for (int i = 0; i < 4; ++i)
#pragma unroll
    for (int j = 0; j < 4; ++j) acc[i][j] = (f32x4){0.f, 0.f, 0.f, 0.f};

  const int r0 = tid >> 2, c0 = (tid & 3) * 8;
  const int r1 = r0 + 64;

  for (int k0 = 0; k0 < Dz; k0 += 32) {
    __syncthreads();
    async16(&lA[r0][c0], A  + (size_t)(m0 + r0) * Dz + k0 + c0);
    async16(&lB[r0][c0], Bt + (size_t)(n0 + r0) * Dz + k0 + c0);
    async16(&lA[r1][c0], A  + (size_t)(m0 + r1) * Dz + k0 + c0);
    async16(&lB[r1][c0], Bt + (size_t)(n0 + r1) * Dz + k0 + c0);
    __syncthreads();
    bf16x8 af[4], bfv[4];
#pragma unroll
    for (int t = 0; t < 4; ++t) {
      af[t]  = *(const bf16x8*)&lA[wm + t * 16 + l16][qd * 8];
      bfv[t] = *(const bf16x8*)&lB[wn + t * 16 + l16][qd * 8];
    }
#pragma unroll
    for (int mt = 0; mt < 4; ++mt)
#pragma unroll
      for (int nt = 0; nt < 4; ++nt)
        acc[mt][nt] = __builtin_amdgcn_mfma_f32_16x16x32_bf16(af[mt], bfv[nt], acc[mt][nt], 0, 0, 0);
  }

#pragma unroll
  for (int nt = 0; nt < 4; ++nt) {
    const int n = n0 + wn + nt * 16 + l16;
    const float bvl = bias[n];
#pragma unroll
    for (int mt = 0; mt < 4; ++mt)
#pragma unroll
      for (int r = 0; r < 4; ++r) {
        const int m = m0 + wm + mt * 16 + qd * 4 + r;
        Cv[(size_t)m * Dz + n] = f2bf(acc[mt][nt][r] + bvl);
      }
  }
}

// -------- FC GEMM: 128(M)x64(N) tile, fp32 out --------
__global__ void __launch_bounds__(256)
gemm_fc(const u16* __restrict__ A, const u16* __restrict__ Bt,
        const float* __restrict__ bias, float* __restrict__ C)
{
  __shared__ __align__(16) u16 lA[128][32];
  __shared__ __align__(16) u16 lB[64][32];
  const int m0 = blockIdx.y * 128, n0 = blockIdx.x * 64;
  const int tid = threadIdx.x;
  const int w = tid >> 6, lane = tid & 63;
  const int wm = (w >> 1) * 64, wn = (w & 1) * 32;
  const int l16 = lane & 15, qd = lane >> 4;

  f32x4 acc[4][2];
#pragma unroll
  for (int i = 0; i < 4; ++i)
#pragma unroll
    for (int j = 0; j < 2; ++j) acc[i][j] = (f32x4){0.f, 0.f, 0.f, 0.f};

  const int r0 = tid >> 2, c0 = (tid & 3) * 8;

  for (int k0 = 0; k0 < Dz; k0 += 32) {
    __syncthreads();
    async16(&lA[r0][c0],      A  + (size_t)(m0 + r0) * Dz + k0 + c0);
    async16(&lA[r0 + 64][c0], A  + (size_t)(m0 + r0 + 64) * Dz + k0 + c0);
    async16(&lB[r0][c0],      Bt + (size_t)(n0 + r0) * Dz + k0 + c0);
    __syncthreads();
    bf16x8 af[4], bfv[2];
#pragma unroll
    for (int t = 0; t < 4; ++t)
      af[t] = *(const bf16x8*)&lA[wm + t * 16 + l16][qd * 8];
#pragma unroll
    for (int t = 0; t < 2; ++t)
      bfv[t] = *(const bf16x8*)&lB[wn + t * 16 + l16][qd * 8];
#pragma unroll
    for (int mt = 0; mt < 4; ++mt)
#pragma unroll
      for (int nt = 0; nt < 2; ++nt)
        acc[mt][nt] = __builtin_amdgcn_mfma_f32_16x16x32_bf16(af[mt], bfv[nt], acc[mt][nt], 0, 0, 0);
  }

#pragma unroll
  for (int nt = 0; nt < 2; ++nt) {
    const int n = n0 + wn + nt * 16 + l16;
    const float bvl = bias[n];
#pragma unroll
    for (int mt = 0; mt < 4; ++mt)
#pragma unroll
      for (int r = 0; r < 4; ++r) {
        const int m = m0 + wm + mt * 16 + qd * 4 + r;
        C[(size_t)m * Dz + n] = acc[mt][nt][r] + bvl;
      }
  }
}

// ---------------- fused attention v5: staged K/V + S^T + register P^T transform ----------------
// grid (S/128, B*H), block 256 (4 waves; wave w owns q-rows [w*32, w*32+32)).
// S^T = K·Q^T (staged lK, round-6). P^T assembled IN REGISTERS from S^T C-layout via
// 2 shfl + 1 cndmask per packed reg (round-5-proven transform) -> no lP, LDS 35.3 KB,
// 3 blocks/CU. O^T = V^T·P^T with V^T A-frags from lV. Row sums via ones-A MFMA.
__global__ void __launch_bounds__(256, 3)
attn_kernel(const u16* __restrict__ Qp, const u16* __restrict__ Kp,
            const u16* __restrict__ Vt, u16* __restrict__ Ao)
{
  __shared__ __align__(16) u16 lK[128][72];     // 18 KB, stride 144 B (≡16 mod 128)
  __shared__ __align__(16) u16 lV[64][136];     // 17 KB, stride 272 B

  const int q0 = blockIdx.x * 128;
  const int bh = blockIdx.y;
  const int b = bh >> 4, h = bh & 15;
  const int tid = threadIdx.x, w = tid >> 6, lane = tid & 63;
  const int l16 = lane & 15, qd = lane >> 4;

  const int krow = tid >> 3, kcol = (tid & 7) * 8;    // + p*32 rows
  const int vrow = tid >> 4, vcol = (tid & 15) * 8;   // + p*16 rows

  // prefetch tile 0 into registers
  u16x8 kreg[4], vreg[4];
#pragma unroll
  for (int p = 0; p < 4; ++p) {
    kreg[p] = *(const u16x8*)(Kp + (size_t)(b * Sz + p * 32 + krow) * Dz + h * 64 + kcol);
    vreg[p] = *(const u16x8*)(Vt + (size_t)(bh * 64 + p * 16 + vrow) * Sz + vcol);
  }

  // Q fragments (B-operand of K·Q^T), loaded once
  bf16x8 qf[2][2];
#pragma unroll
  for (int qt = 0; qt < 2; ++qt)
#pragma unroll
    for (int ksd = 0; ksd < 2; ++ksd)
      qf[qt][ksd] = *(const bf16x8*)(Qp + (size_t)(b * Sz + q0 + w * 32 + qt * 16 + l16) * Dz
                                     + h * 64 + ksd * 32 + qd * 8);

  // ones A-fragment (bf16 1.0) for row sums
  u16x8 ob;
#pragma unroll
  for (int i = 0; i < 8; ++i) ob[i] = 0x3F80u;
  const bf16x8 onesA = __builtin_bit_cast(bf16x8, ob);

  // transform source-lane indices (round-5-proven): qd_s = (qd&1)*2 + (i>>1), same l16
  const int sidx0 = ((qd & 1) * 2) * 16 + l16;

  f32x4 oaccT[4][2];   // O^T C-layout: rows hd = mt*16+qd*4+r, cols q = qt*16+l16
  f32x4 laccT[2];
#pragma unroll
  for (int mt = 0; mt < 4; ++mt)
#pragma unroll
    for (int qt = 0; qt < 2; ++qt) oaccT[mt][qt] = (f32x4){0.f, 0.f, 0.f, 0.f};
  laccT[0] = (f32x4){0.f, 0.f, 0.f, 0.f};
  laccT[1] = (f32x4){0.f, 0.f, 0.f, 0.f};

  for (int t = 0; t < Sz / 128; ++t) {
    __syncthreads();
#pragma unroll
    for (int p = 0; p < 4; ++p) {
      *(u16x8*)&lK[p * 32 + krow][kcol] = kreg[p];
      *(u16x8*)&lV[p * 16 + vrow][vcol] = vreg[p];
    }
    if (t + 1 < Sz / 128) {
      const int kv = (t + 1) * 128;
#pragma unroll
      for (int p = 0; p < 4; ++p) {
        kreg[p] = *(const u16x8*)(Kp + (size_t)(b * Sz + kv + p * 32 + krow) * Dz + h * 64 + kcol);
        vreg[p] = *(const u16x8*)(Vt + (size_t)(bh * 64 + p * 16 + vrow) * Sz + kv + vcol);
      }
    }
    __syncthreads();

    // S^T = K @ Q^T : st[kvt][qt], C rows = kv (kvt*16+qd*4+r), cols = q (qt*16+l16)
    f32x4 st[8][2];
#pragma unroll
    for (int i = 0; i < 8; ++i)
#pragma unroll
      for (int j = 0; j < 2; ++j) st[i][j] = (f32x4){0.f, 0.f, 0.f, 0.f};
#pragma unroll
    for (int ksd = 0; ksd < 2; ++ksd) {
      bf16x8 kf[8];
#pragma unroll
      for (int kvt = 0; kvt < 8; ++kvt)
        kf[kvt] = *(const bf16x8*)&lK[kvt * 16 + l16][ksd * 32 + qd * 8];
#pragma unroll
      for (int kvt = 0; kvt < 8; ++kvt)
#pragma unroll
        for (int qt = 0; qt < 2; ++qt)
          st[kvt][qt] = __builtin_amdgcn_mfma_f32_16x16x32_bf16(kf[kvt], qf[qt][ksd], st[kvt][qt], 0, 0, 0);
    }

    // per 32-kv chunk: exp -> pack -> register transform to P^T B-frags -> O^T/l MFMA
#pragma unroll
    for (int ks = 0; ks < 4; ++ks) {
      unsigned pkl[2][2][2];   // [half (kvt&1)][qt][pair]
#pragma unroll
      for (int j = 0; j < 2; ++j)
#pragma unroll
        for (int qt = 0; qt < 2; ++qt) {
          const f32x4 s4 = st[2 * ks + j][qt];
          float e0 = exp2f(s4[0] * C1);
          float e1 = exp2f(s4[1] * C1);
          float e2 = exp2f(s4[2] * C1);
          float e3 = exp2f(s4[3] * C1);
          pkl[j][qt][0] = packbf(e0, e1);
          pkl[j][qt][1] = packbf(e2, e3);
        }

      bf16x8 vfA[4];   // V^T A-frags: m = hd (mt*16+l16), k = kv (ks*32+qd*8..+7)
#pragma unroll
      for (int mt = 0; mt < 4; ++mt)
        vfA[mt] = *(const bf16x8*)&lV[mt * 16 + l16][ks * 32 + qd * 8];

#pragma unroll
      for (int qt = 0; qt < 2; ++qt) {
        unsigned v[4];
#pragma unroll
        for (int i = 0; i < 4; ++i) {
          const int si = sidx0 + (i >> 1) * 16;
          unsigned tA = (unsigned)__shfl((int)pkl[0][qt][i & 1], si);
          unsigned tB = (unsigned)__shfl((int)pkl[1][qt][i & 1], si);
          v[i] = (qd & 2) ? tB : tA;
        }
        const bf16x8 pb = mk8(v[0], v[1], v[2], v[3]);
#pragma unroll
        for (int mt = 0; mt < 4; ++mt)
          oaccT[mt][qt] = __builtin_amdgcn_mfma_f32_16x16x32_bf16(vfA[mt], pb, oaccT[mt][qt], 0, 0, 0);
        laccT[qt] = __builtin_amdgcn_mfma_f32_16x16x32_bf16(onesA, pb, laccT[qt], 0, 0, 0);
      }
    }
  }

  // normalize + store (round-5-proven epilogue): lane writes 4 consecutive hd per q
  float inv[2];
  inv[0] = 1.0f / laccT[0][0];
  inv[1] = 1.0f / laccT[1][0];
#pragma unroll
  for (int mt = 0; mt < 4; ++mt)
#pragma unroll
    for (int qt = 0; qt < 2; ++qt) {
      const int q = b * Sz + q0 + w * 32 + qt * 16 + l16;
      ushort4 o = make_ushort4(f2bf(oaccT[mt][qt][0] * inv[qt]),
                               f2bf(oaccT[mt][qt][1] * inv[qt]),
                               f2bf(oaccT[mt][qt][2] * inv[qt]),
                               f2bf(oaccT[mt][qt][3] * inv[qt]));
      *(ushort4*)(Ao + (size_t)q * Dz + h * 64 + mt * 16 + qd * 4) = o;
    }
}

// ---------------- host launch ----------------
extern "C" void kernel_launch(void* const* d_in, const int* in_sizes, int n_in,
                              void* d_out, int out_size, void* d_ws, size_t ws_size,
                              hipStream_t stream) {
  const float* query = (const float*)d_in[0];
  const float* key   = (const float*)d_in[1];
  const float* value = (const float*)d_in[2];
  const float* w_q  = (const float*)d_in[3];
  const float* b_q  = (const float*)d_in[4];
  const float* w_k  = (const float*)d_in[5];
  const float* b_k  = (const float*)d_in[6];
  const float* w_v  = (const float*)d_in[7];
  const float* b_v  = (const float*)d_in[8];
  const float* w_fc = (const float*)d_in[9];
  const float* b_fc = (const float*)d_in[10];
  float* out = (float*)d_out;

  const size_t XE = (size_t)Mz * Dz;   // 4 Mi elements
  const size_t WE = (size_t)Dz * Dz;   // 1 Mi elements
  u16* Xq  = (u16*)d_ws;               // bf16 inputs
  u16* Xk  = Xq + XE;
  u16* Xv  = Xk + XE;
  u16* Wt  = Xv + XE;                  // 4 stacked transposed weights [N][K]: q,k,v,fc
  u16* Wtf = Wt + 3 * WE;
  u16* Qp  = Wt + 4 * WE;              // projections
  u16* Kp  = Qp + XE;
  u16* Vp  = Kp + XE;
  u16* Vt  = Xk;                       // reuse: Xk dead after QKV projections
  u16* Ao  = Xq;                       // reuse: Xq dead after QKV projections

  prep_kernel<<<16384, 256, 0, stream>>>(query, key, value, w_q, w_k, w_v, w_fc,
                                         Xq, Xk, Xv, Wt);

  gemm_qkv<<<dim3(24, Mz / 128), 256, 0, stream>>>(Xq, Xk, Xv, Wt, b_q, b_k, b_v, Qp, Kp, Vp);

  vtrans_kernel<<<dim3(Sz / 64, Bz * Hz), 256, 0, stream>>>(Vp, Vt);

  attn_kernel<<<dim3(Sz / 128, Bz * Hz), 256, 0, stream>>>(Qp, Kp, Vt, Ao);

  gemm_fc<<<dim3(Dz / 64, Mz / 128), 256, 0, stream>>>(Ao, Wtf, b_fc, out);
}

// Round 8
// 276.524 us; speedup vs baseline: 1.0835x; 1.0835x over previous
//
#include <hip/hip_runtime.h>
#include <stdint.h>

#define Bz 2
#define Sz 2048
#define Dz 1024
#define Hz 16
#define HDz 64
#define Mz (Bz*Sz)   // 4096

typedef unsigned short u16;
typedef __attribute__((ext_vector_type(8))) __bf16 bf16x8;
typedef __attribute__((ext_vector_type(8))) unsigned short u16x8;
typedef __attribute__((ext_vector_type(4))) float f32x4;

#define C1 0.1803368801111243f   /* 0.125 * log2(e) */

__device__ __forceinline__ u16 f2bf(float f) {
  union { float f; unsigned u; } v; v.f = f;
  unsigned r = v.u + 0x7fffu + ((v.u >> 16) & 1u);
  return (u16)(r >> 16);
}

// pack two fp32 into adjacent bf16 (round-half-up), low = a, high = b
__device__ __forceinline__ unsigned packbf(float a, float b) {
  unsigned ua = __builtin_bit_cast(unsigned, a);
  unsigned ub = __builtin_bit_cast(unsigned, b);
  return ((ua + 0x8000u) >> 16) | ((ub + 0x8000u) & 0xFFFF0000u);
}

__device__ __forceinline__ bf16x8 mk8(unsigned a, unsigned b, unsigned c, unsigned d) {
  union { unsigned u[4]; bf16x8 v; } x;
  x.u[0] = a; x.u[1] = b; x.u[2] = c; x.u[3] = d;
  return x.v;
}

__device__ __forceinline__ void async16(void* lds, const void* g) {
  __builtin_amdgcn_global_load_lds(
      (const __attribute__((address_space(1))) unsigned int*)g,
      (__attribute__((address_space(3))) unsigned int*)lds, 16, 0, 0);
}

// ---------- fused prep: fp32->bf16 for q/k/v AND weight transpose+convert ----------
__global__ void __launch_bounds__(256)
prep_kernel(const float* __restrict__ q, const float* __restrict__ k, const float* __restrict__ v,
            const float* __restrict__ w0, const float* __restrict__ w1,
            const float* __restrict__ w2, const float* __restrict__ w3,
            u16* __restrict__ xq, u16* __restrict__ xk, u16* __restrict__ xv,
            u16* __restrict__ Wt) {
  __shared__ __align__(16) float t[32][33];
  const int bid = blockIdx.x, tid = threadIdx.x;
  if (bid < 12288) {
    const int sel = bid >> 12;
    const int i = ((bid & 4095) << 8) + tid;
    const float* in = sel == 0 ? q : sel == 1 ? k : v;
    u16* out = sel == 0 ? xq : sel == 1 ? xk : xv;
    float4 tv = ((const float4*)in)[i];
    ((ushort4*)out)[i] = make_ushort4(f2bf(tv.x), f2bf(tv.y), f2bf(tv.z), f2bf(tv.w));
  } else {
    const int idx = bid - 12288;
    const int z = idx >> 10, r = idx & 1023;
    const int n0 = (r & 31) * 32, k0 = (r >> 5) * 32;
    const float* W = z == 0 ? w0 : z == 1 ? w1 : z == 2 ? w2 : w3;
    u16* o = Wt + (size_t)z * Dz * Dz;
    const int x = tid & 31, y = tid >> 5;   // 32 x 8
#pragma unroll
    for (int i = 0; i < 4; ++i)
      t[y + i*8][x] = W[(size_t)(k0 + y + i*8) * Dz + n0 + x];
    __syncthreads();
#pragma unroll
    for (int i = 0; i < 4; ++i)
      o[(size_t)(n0 + y + i*8) * Dz + k0 + x] = f2bf(t[x][y + i*8]);
  }
}

// ---- Vp[B*S][D] bf16 -> Vt[B][H][HD][S] bf16 (per-head transpose, coalesced) ----
__global__ void __launch_bounds__(256)
vtrans_kernel(const u16* __restrict__ Vp, u16* __restrict__ Vt) {
  __shared__ __align__(16) u16 t[64][72];
  int s0 = blockIdx.x * 64, bh = blockIdx.y;
  int b = bh >> 4;
  int h = bh & 15;
  int tid = threadIdx.x;
#pragma unroll
  for (int p = 0; p < 4; ++p) {
    int c = p * 256 + tid;
    int row = c >> 4, off = (c & 15) * 4;
    ushort4 v = *(const ushort4*)(Vp + (size_t)(b * Sz + s0 + row) * Dz + h * 64 + off);
    *(ushort4*)&t[row][off] = v;
  }
  __syncthreads();
#pragma unroll
  for (int p = 0; p < 4; ++p) {
    int c = p * 256 + tid;
    int d = c >> 4, sc = (c & 15) * 4;
    ushort4 v = make_ushort4(t[sc + 0][d], t[sc + 1][d], t[sc + 2][d], t[sc + 3][d]);
    *(ushort4*)(Vt + (size_t)(bh * 64 + d) * Sz + s0 + sc) = v;
  }
}

// -------- fused QKV GEMM: 128x128 tile; blockIdx.x>>3 selects {Q,K,V}; plain epilogue --------
__global__ void __launch_bounds__(256)
gemm_qkv(const u16* __restrict__ xq, const u16* __restrict__ xk, const u16* __restrict__ xv,
         const u16* __restrict__ Wt3,
         const float* __restrict__ bq, const float* __restrict__ bk, const float* __restrict__ bv,
         u16* __restrict__ Qp, u16* __restrict__ Kp, u16* __restrict__ Vp)
{
  __shared__ __align__(16) u16 lA[128][32];
  __shared__ __align__(16) u16 lB[128][32];
  const int sel = blockIdx.x >> 3;
  const int n0 = (blockIdx.x & 7) * 128;
  const int m0 = blockIdx.y * 128;
  const u16* A = sel == 0 ? xq : sel == 1 ? xk : xv;
  const u16* Bt = Wt3 + (size_t)sel * Dz * Dz;
  const float* bias = sel == 0 ? bq : sel == 1 ? bk : bv;
  u16* Cv = sel == 0 ? Qp : sel == 1 ? Kp : Vp;

  const int tid = threadIdx.x;
  const int w = tid >> 6, lane = tid & 63;
  const int wm = (w >> 1) * 64, wn = (w & 1) * 64;
  const int l16 = lane & 15, qd = lane >> 4;

  f32x4 acc[4][4];
#pragma unroll
  for (int i = 0; i < 4; ++i)
#pragma unroll
    for (int j = 0; j < 4; ++j) acc[i][j] = (f32x4){0.f, 0.f, 0.f, 0.f};

  const int r0 = tid >> 2, c0 = (tid & 3) * 8;
  const int r1 = r0 + 64;

  for (int k0 = 0; k0 < Dz; k0 += 32) {
    __syncthreads();
    async16(&lA[r0][c0], A  + (size_t)(m0 + r0) * Dz + k0 + c0);
    async16(&lB[r0][c0], Bt + (size_t)(n0 + r0) * Dz + k0 + c0);
    async16(&lA[r1][c0], A  + (size_t)(m0 + r1) * Dz + k0 + c0);
    async16(&lB[r1][c0], Bt + (size_t)(n0 + r1) * Dz + k0 + c0);
    __syncthreads();
    bf16x8 af[4], bfv[4];
#pragma unroll
    for (int t = 0; t < 4; ++t) {
      af[t]  = *(const bf16x8*)&lA[wm + t * 16 + l16][qd * 8];
      bfv[t] = *(const bf16x8*)&lB[wn + t * 16 + l16][qd * 8];
    }
#pragma unroll
    for (int mt = 0; mt < 4; ++mt)
#pragma unroll
      for (int nt = 0; nt < 4; ++nt)
        acc[mt][nt] = __builtin_amdgcn_mfma_f32_16x16x32_bf16(af[mt], bfv[nt], acc[mt][nt], 0, 0, 0);
  }

#pragma unroll
  for (int nt = 0; nt < 4; ++nt) {
    const int n = n0 + wn + nt * 16 + l16;
    const float bvl = bias[n];
#pragma unroll
    for (int mt = 0; mt < 4; ++mt)
#pragma unroll
      for (int r = 0; r < 4; ++r) {
        const int m = m0 + wm + mt * 16 + qd * 4 + r;
        Cv[(size_t)m * Dz + n] = f2bf(acc[mt][nt][r] + bvl);
      }
  }
}

// -------- FC GEMM: 128(M)x64(N) tile, fp32 out --------
__global__ void __launch_bounds__(256)
gemm_fc(const u16* __restrict__ A, const u16* __restrict__ Bt,
        const float* __restrict__ bias, float* __restrict__ C)
{
  __shared__ __align__(16) u16 lA[128][32];
  __shared__ __align__(16) u16 lB[64][32];
  const int m0 = blockIdx.y * 128, n0 = blockIdx.x * 64;
  const int tid = threadIdx.x;
  const int w = tid >> 6, lane = tid & 63;
  const int wm = (w >> 1) * 64, wn = (w & 1) * 32;
  const int l16 = lane & 15, qd = lane >> 4;

  f32x4 acc[4][2];
#pragma unroll
  for (int i = 0; i < 4; ++i)
#pragma unroll
    for (int j = 0; j < 2; ++j) acc[i][j] = (f32x4){0.f, 0.f, 0.f, 0.f};

  const int r0 = tid >> 2, c0 = (tid & 3) * 8;

  for (int k0 = 0; k0 < Dz; k0 += 32) {
    __syncthreads();
    async16(&lA[r0][c0],      A  + (size_t)(m0 + r0) * Dz + k0 + c0);
    async16(&lA[r0 + 64][c0], A  + (size_t)(m0 + r0 + 64) * Dz + k0 + c0);
    async16(&lB[r0][c0],      Bt + (size_t)(n0 + r0) * Dz + k0 + c0);
    __syncthreads();
    bf16x8 af[4], bfv[2];
#pragma unroll
    for (int t = 0; t < 4; ++t)
      af[t] = *(const bf16x8*)&lA[wm + t * 16 + l16][qd * 8];
#pragma unroll
    for (int t = 0; t < 2; ++t)
      bfv[t] = *(const bf16x8*)&lB[wn + t * 16 + l16][qd * 8];
#pragma unroll
    for (int mt = 0; mt < 4; ++mt)
#pragma unroll
      for (int nt = 0; nt < 2; ++nt)
        acc[mt][nt] = __builtin_amdgcn_mfma_f32_16x16x32_bf16(af[mt], bfv[nt], acc[mt][nt], 0, 0, 0);
  }

#pragma unroll
  for (int nt = 0; nt < 2; ++nt) {
    const int n = n0 + wn + nt * 16 + l16;
    const float bvl = bias[n];
#pragma unroll
    for (int mt = 0; mt < 4; ++mt)
#pragma unroll
      for (int r = 0; r < 4; ++r) {
        const int m = m0 + wm + mt * 16 + qd * 4 + r;
        C[(size_t)m * Dz + n] = acc[mt][nt][r] + bvl;
      }
  }
}

// ---------------- fused attention v6: v5 structure, spill-free at 3 blocks/CU ----------------
// grid (S/128, B*H), block 256 (4 waves; wave w owns q-rows [w*32, w*32+32)).
// vs v5 (round 7, spilled at bounds(256,3)): S^T-compute and softmax/PV interleaved at
// 32-kv granularity so only st[2][2] (16 regs) is live (was st[8][2]=64); row sums via
// VALU partials + end butterfly (round-5-proven) instead of ones-MFMA (saves 12 regs).
// Live set ~150 < 170 cap -> no scratch. LDS 35.3 KB -> 3 blocks/CU.
__global__ void __launch_bounds__(256, 3)
attn_kernel(const u16* __restrict__ Qp, const u16* __restrict__ Kp,
            const u16* __restrict__ Vt, u16* __restrict__ Ao)
{
  __shared__ __align__(16) u16 lK[128][72];     // 18 KB, stride 144 B (≡16 mod 128)
  __shared__ __align__(16) u16 lV[64][136];     // 17 KB, stride 272 B

  const int q0 = blockIdx.x * 128;
  const int bh = blockIdx.y;
  const int b = bh >> 4, h = bh & 15;
  const int tid = threadIdx.x, w = tid >> 6, lane = tid & 63;
  const int l16 = lane & 15, qd = lane >> 4;

  const int krow = tid >> 3, kcol = (tid & 7) * 8;    // + p*32 rows
  const int vrow = tid >> 4, vcol = (tid & 15) * 8;   // + p*16 rows

  // prefetch tile 0 into registers
  u16x8 kreg[4], vreg[4];
#pragma unroll
  for (int p = 0; p < 4; ++p) {
    kreg[p] = *(const u16x8*)(Kp + (size_t)(b * Sz + p * 32 + krow) * Dz + h * 64 + kcol);
    vreg[p] = *(const u16x8*)(Vt + (size_t)(bh * 64 + p * 16 + vrow) * Sz + vcol);
  }

  // Q fragments (B-operand of K·Q^T), loaded once
  bf16x8 qf[2][2];
#pragma unroll
  for (int qt = 0; qt < 2; ++qt)
#pragma unroll
    for (int ksd = 0; ksd < 2; ++ksd)
      qf[qt][ksd] = *(const bf16x8*)(Qp + (size_t)(b * Sz + q0 + w * 32 + qt * 16 + l16) * Dz
                                     + h * 64 + ksd * 32 + qd * 8);

  // transform source-lane indices (round-5-proven): qd_s = (qd&1)*2 + (i>>1), same l16
  const int sidx0 = ((qd & 1) * 2) * 16 + l16;

  f32x4 oaccT[4][2];   // O^T C-layout: rows hd = mt*16+qd*4+r, cols q = qt*16+l16
#pragma unroll
  for (int mt = 0; mt < 4; ++mt)
#pragma unroll
    for (int qt = 0; qt < 2; ++qt) oaccT[mt][qt] = (f32x4){0.f, 0.f, 0.f, 0.f};
  float lsum[2] = {0.f, 0.f};

  for (int t = 0; t < Sz / 128; ++t) {
    __syncthreads();
#pragma unroll
    for (int p = 0; p < 4; ++p) {
      *(u16x8*)&lK[p * 32 + krow][kcol] = kreg[p];
      *(u16x8*)&lV[p * 16 + vrow][vcol] = vreg[p];
    }
    if (t + 1 < Sz / 128) {
      const int kv = (t + 1) * 128;
#pragma unroll
      for (int p = 0; p < 4; ++p) {
        kreg[p] = *(const u16x8*)(Kp + (size_t)(b * Sz + kv + p * 32 + krow) * Dz + h * 64 + kcol);
        vreg[p] = *(const u16x8*)(Vt + (size_t)(bh * 64 + p * 16 + vrow) * Sz + kv + vcol);
      }
    }
    __syncthreads();

    // interleaved: per 32-kv chunk, S^T MFMAs -> exp/pack -> register P^T -> PV MFMAs
#pragma unroll
    for (int ks = 0; ks < 4; ++ks) {
      // S^T = K @ Q^T for kv rows [ks*32, ks*32+32): st[j][qt], j = kvt&1
      f32x4 st[2][2];
#pragma unroll
      for (int j = 0; j < 2; ++j)
#pragma unroll
        for (int qt = 0; qt < 2; ++qt) st[j][qt] = (f32x4){0.f, 0.f, 0.f, 0.f};
#pragma unroll
      for (int ksd = 0; ksd < 2; ++ksd) {
        bf16x8 kf0 = *(const bf16x8*)&lK[(2 * ks    ) * 16 + l16][ksd * 32 + qd * 8];
        bf16x8 kf1 = *(const bf16x8*)&lK[(2 * ks + 1) * 16 + l16][ksd * 32 + qd * 8];
#pragma unroll
        for (int qt = 0; qt < 2; ++qt) {
          st[0][qt] = __builtin_amdgcn_mfma_f32_16x16x32_bf16(kf0, qf[qt][ksd], st[0][qt], 0, 0, 0);
          st[1][qt] = __builtin_amdgcn_mfma_f32_16x16x32_bf16(kf1, qf[qt][ksd], st[1][qt], 0, 0, 0);
        }
      }

      // exp + pack + VALU row-sum partials
      unsigned pkl[2][2][2];   // [half][qt][pair]
#pragma unroll
      for (int j = 0; j < 2; ++j)
#pragma unroll
        for (int qt = 0; qt < 2; ++qt) {
          float e0 = exp2f(st[j][qt][0] * C1);
          float e1 = exp2f(st[j][qt][1] * C1);
          float e2 = exp2f(st[j][qt][2] * C1);
          float e3 = exp2f(st[j][qt][3] * C1);
          lsum[qt] += (e0 + e1) + (e2 + e3);
          pkl[j][qt][0] = packbf(e0, e1);
          pkl[j][qt][1] = packbf(e2, e3);
        }

      bf16x8 vfA[4];   // V^T A-frags: m = hd (mt*16+l16), k = kv (ks*32+qd*8..+7)
#pragma unroll
      for (int mt = 0; mt < 4; ++mt)
        vfA[mt] = *(const bf16x8*)&lV[mt * 16 + l16][ks * 32 + qd * 8];

#pragma unroll
      for (int qt = 0; qt < 2; ++qt) {
        unsigned v[4];
#pragma unroll
        for (int i = 0; i < 4; ++i) {
          const int si = sidx0 + (i >> 1) * 16;
          unsigned tA = (unsigned)__shfl((int)pkl[0][qt][i & 1], si);
          unsigned tB = (unsigned)__shfl((int)pkl[1][qt][i & 1], si);
          v[i] = (qd & 2) ? tB : tA;
        }
        const bf16x8 pb = mk8(v[0], v[1], v[2], v[3]);
#pragma unroll
        for (int mt = 0; mt < 4; ++mt)
          oaccT[mt][qt] = __builtin_amdgcn_mfma_f32_16x16x32_bf16(vfA[mt], pb, oaccT[mt][qt], 0, 0, 0);
      }
    }
  }

  // finish row sums: lane holds partial over its qd's kv rows; butterfly across quads
  float inv[2];
#pragma unroll
  for (int qt = 0; qt < 2; ++qt) {
    float lq = lsum[qt];
    lq += __shfl_xor(lq, 16);
    lq += __shfl_xor(lq, 32);
    inv[qt] = 1.0f / lq;
  }

  // store O (lane writes 4 consecutive hd per q; round-5-proven epilogue)
#pragma unroll
  for (int mt = 0; mt < 4; ++mt)
#pragma unroll
    for (int qt = 0; qt < 2; ++qt) {
      const int q = b * Sz + q0 + w * 32 + qt * 16 + l16;
      ushort4 o = make_ushort4(f2bf(oaccT[mt][qt][0] * inv[qt]),
                               f2bf(oaccT[mt][qt][1] * inv[qt]),
                               f2bf(oaccT[mt][qt][2] * inv[qt]),
                               f2bf(oaccT[mt][qt][3] * inv[qt]));
      *(ushort4*)(Ao + (size_t)q * Dz + h * 64 + mt * 16 + qd * 4) = o;
    }
}

// ---------------- host launch ----------------
extern "C" void kernel_launch(void* const* d_in, const int* in_sizes, int n_in,
                              void* d_out, int out_size, void* d_ws, size_t ws_size,
                              hipStream_t stream) {
  const float* query = (const float*)d_in[0];
  const float* key   = (const float*)d_in[1];
  const float* value = (const float*)d_in[2];
  const float* w_q  = (const float*)d_in[3];
  const float* b_q  = (const float*)d_in[4];
  const float* w_k  = (const float*)d_in[5];
  const float* b_k  = (const float*)d_in[6];
  const float* w_v  = (const float*)d_in[7];
  const float* b_v  = (const float*)d_in[8];
  const float* w_fc = (const float*)d_in[9];
  const float* b_fc = (const float*)d_in[10];
  float* out = (float*)d_out;

  const size_t XE = (size_t)Mz * Dz;   // 4 Mi elements
  const size_t WE = (size_t)Dz * Dz;   // 1 Mi elements
  u16* Xq  = (u16*)d_ws;               // bf16 inputs
  u16* Xk  = Xq + XE;
  u16* Xv  = Xk + XE;
  u16* Wt  = Xv + XE;                  // 4 stacked transposed weights [N][K]: q,k,v,fc
  u16* Wtf = Wt + 3 * WE;
  u16* Qp  = Wt + 4 * WE;              // projections
  u16* Kp  = Qp + XE;
  u16* Vp  = Kp + XE;
  u16* Vt  = Xk;                       // reuse: Xk dead after QKV projections
  u16* Ao  = Xq;                       // reuse: Xq dead after QKV projections

  prep_kernel<<<16384, 256, 0, stream>>>(query, key, value, w_q, w_k, w_v, w_fc,
                                         Xq, Xk, Xv, Wt);

  gemm_qkv<<<dim3(24, Mz / 128), 256, 0, stream>>>(Xq, Xk, Xv, Wt, b_q, b_k, b_v, Qp, Kp, Vp);

  vtrans_kernel<<<dim3(Sz / 64, Bz * Hz), 256, 0, stream>>>(Vp, Vt);

  attn_kernel<<<dim3(Sz / 128, Bz * Hz), 256, 0, stream>>>(Qp, Kp, Vt, Ao);

  gemm_fc<<<dim3(Dz / 64, Mz / 128), 256, 0, stream>>>(Ao, Wtf, b_fc, out);
}